// Round 2
// baseline (8549.113 us; speedup 1.0000x reference)
//
#include <hip/hip_runtime.h>
#include <hip/hip_bf16.h>

// Video_multilevel_encoding — round 2: dual-dtype (runtime-probed bf16 vs f32 inputs),
// compact 98.6 MB workspace (pre/Mp/convD stored bf16).
// Algebraic facts carried forward:
//   * attention softmax over size-1 axis == 1 -> H2 == gru (att weights dead)
//   * convs == NT-GEMM over masked gru rows + shift-add/max epilogue
//   * GRU is contractive; all math NaN-free for finite inputs.

#define T_SEQ 80

__device__ __forceinline__ float bf2f(unsigned short s) {
    union { unsigned int u; float f; } c; c.u = ((unsigned int)s) << 16; return c.f;
}
__device__ __forceinline__ unsigned short f2bf(float f) {
    union { float f; unsigned int u; } c; c.f = f;
    unsigned int u = c.u;
    u += 0x7fffu + ((u >> 16) & 1u);   // RNE
    return (unsigned short)(u >> 16);
}
// scalar load from input tensor: f32m=1 -> f32, else bf16
__device__ __forceinline__ float ldsc(const void* p, long i, int f32m) {
    return f32m ? ((const float*)p)[i] : bf2f(((const unsigned short*)p)[i]);
}
// 8-wide vector load (16B for bf16, 32B for f32); i must be 8-aligned (f32: 4-aligned suffices)
__device__ __forceinline__ void ld8(const void* p, long i, int f32m, float* o) {
    if (f32m) {
        const float* q = (const float*)p + i;
        float4 a = *(const float4*)q, b = *(const float4*)(q + 4);
        o[0]=a.x; o[1]=a.y; o[2]=a.z; o[3]=a.w; o[4]=b.x; o[5]=b.y; o[6]=b.z; o[7]=b.w;
    } else {
        uint4 v = *(const uint4*)((const unsigned short*)p + i);
        o[0]=bf2f((unsigned short)(v.x & 0xffffu)); o[1]=bf2f((unsigned short)(v.x >> 16));
        o[2]=bf2f((unsigned short)(v.y & 0xffffu)); o[3]=bf2f((unsigned short)(v.y >> 16));
        o[4]=bf2f((unsigned short)(v.z & 0xffffu)); o[5]=bf2f((unsigned short)(v.z >> 16));
        o[6]=bf2f((unsigned short)(v.w & 0xffffu)); o[7]=bf2f((unsigned short)(v.w >> 16));
    }
}

// Probe: decide whether float tensors are stored f32 (flag=1) or bf16 (flag=0).
// bf16-decode 256 ushorts of videos~N(0,1): true bf16 -> ~0 implausible values;
// f32 misread as bf16 -> low-mantissa halves have uniform exponents -> ~100 implausible.
__global__ void k_probe(const unsigned short* __restrict__ v, int* __restrict__ flag) {
    int tid = threadIdx.x;  // 64
    int bad = 0;
    #pragma unroll
    for (int u = 0; u < 4; ++u) {
        float x = bf2f(v[tid * 4 + u]);
        float ax = fabsf(x);
        if (!(ax <= 64.f) || (ax != 0.f && ax < 9.094947e-13f)) bad++;  // !(<=) catches NaN/Inf
    }
    #pragma unroll
    for (int off = 32; off >= 1; off >>= 1) bad += __shfl_down(bad, off, 64);
    if (tid == 0) *flag = (bad >= 16) ? 1 : 0;
}

// ---------------------------------------------------------------------------
// NT-GEMM: C[m,n] = sum_k A[m,k]*B[n,k] (+bias[n]).
// AMODE: 0 = A is ws f32, 1 = A is ws bf16, 2 = A is input tensor (flag-selected).
// OUTBF: 1 -> bf16 C, 0 -> f32 C. B/bias are input tensors (flag-selected).
// A row offset = a_base + (m/a_rpb)*a_bstride + (m%a_rpb)*a_rstride.
// B row r = n - d*n_split (d = n>=n_split), elem idx (r%b_mod)*b_sa + (r/b_mod)*b_sb.
// C idx = (d?out_dsplit:0) + m*ldc + r.
// Tile 128x128, BK=16, 256 threads, 8x8 register tile. M,N mult of 128; K mult of 16.
// ---------------------------------------------------------------------------
template<int AMODE, int OUTBF>
__global__ __launch_bounds__(256) void gemm_nt(
    const void* __restrict__ Av, long a_base, int a_rpb, long a_bstride, int a_rstride,
    const void* __restrict__ B1, const void* __restrict__ B2,
    int n_split, int b_mod, long b_sa, long b_sb,
    const void* __restrict__ bias1, const void* __restrict__ bias2, int has_bias,
    void* __restrict__ Cout, long out_dsplit, long ldc, int K,
    const int* __restrict__ dtf)
{
    const int f32m = *dtf;
    __shared__ float As[16][132];
    __shared__ float Bs[16][132];
    const int tid = threadIdx.x;
    const int m0 = blockIdx.y * 128, n0 = blockIdx.x * 128;

    const int srow = tid >> 1;
    const int k8   = (tid & 1) * 8;
    const int am   = m0 + srow;
    const long aoff = a_base + (long)(am / a_rpb) * a_bstride + (long)(am % a_rpb) * a_rstride + k8;
    const int bn = n0 + srow;
    const int bd = (bn >= n_split) ? 1 : 0;
    const int br = bn - (bd ? n_split : 0);
    const void* Bbase = bd ? B2 : B1;
    const long boff = (long)(br % b_mod) * b_sa + (long)(br / b_mod) * b_sb + k8;

    const int tx = tid & 15, ty = tid >> 4;
    float acc[8][8];
    #pragma unroll
    for (int i = 0; i < 8; ++i)
        #pragma unroll
        for (int j = 0; j < 8; ++j) acc[i][j] = 0.f;

    for (int k0 = 0; k0 < K; k0 += 16) {
        float ta[8], tb[8];
        if (AMODE == 0)      ld8(Av, aoff + k0, 1, ta);
        else if (AMODE == 1) ld8(Av, aoff + k0, 0, ta);
        else                 ld8(Av, aoff + k0, f32m, ta);
        ld8(Bbase, boff + k0, f32m, tb);
        #pragma unroll
        for (int i = 0; i < 8; ++i) As[k8 + i][srow] = ta[i];
        #pragma unroll
        for (int i = 0; i < 8; ++i) Bs[k8 + i][srow] = tb[i];
        __syncthreads();
        #pragma unroll
        for (int kk = 0; kk < 16; ++kk) {
            float a[8], b[8];
            *(float4*)&a[0] = *(const float4*)&As[kk][ty*8];
            *(float4*)&a[4] = *(const float4*)&As[kk][ty*8+4];
            *(float4*)&b[0] = *(const float4*)&Bs[kk][tx*8];
            *(float4*)&b[4] = *(const float4*)&Bs[kk][tx*8+4];
            #pragma unroll
            for (int i = 0; i < 8; ++i)
                #pragma unroll
                for (int j = 0; j < 8; ++j)
                    acc[i][j] += a[i]*b[j];
        }
        __syncthreads();
    }
    #pragma unroll
    for (int i = 0; i < 8; ++i) {
        const long m = m0 + ty*8 + i;
        #pragma unroll
        for (int j = 0; j < 8; ++j) {
            int na = n0 + tx*8 + j;
            int dd = (na >= n_split) ? 1 : 0;
            int g  = na - (dd ? n_split : 0);
            float v = acc[i][j];
            if (has_bias) v += ldsc(dd ? bias2 : bias1, g, f32m);
            long cidx = (dd ? out_dsplit : 0) + m*ldc + g;
            if (OUTBF) ((unsigned short*)Cout)[cidx] = f2bf(v);
            else       ((float*)Cout)[cidx] = v;
        }
    }
}

// Pre-transpose Whh -> Wt f32 [d][gate][k][j] (j contiguous), bhh -> f32.
__global__ __launch_bounds__(256) void k_prep(
    const void* __restrict__ Whh_f, const void* __restrict__ Whh_b,
    const void* __restrict__ bhh_f, const void* __restrict__ bhh_b,
    float* __restrict__ Wt, float* __restrict__ bhh32, const int* __restrict__ dtf)
{
    const int f32m = *dtf;
    int e = blockIdx.x * 256 + threadIdx.x;      // < 1572864
    int k  = e & 511;
    int j  = (e >> 9) & 511;
    int q  = e >> 18;                            // 0..5 = d*3+gate
    int d  = (q >= 3) ? 1 : 0;
    int g3 = q - d * 3;
    Wt[((long)q * 512 + k) * 512 + j] = ldsc(d ? Whh_b : Whh_f, (long)(g3 * 512 + j) * 512 + k, f32m);
    if (e < 3072) {
        int dd = (e >= 1536) ? 1 : 0;
        int g  = e - dd * 1536;
        bhh32[e] = ldsc(dd ? bhh_b : bhh_f, g, f32m);
    }
}

// One GRU step, both directions. pre: bf16 [d][b*80+t][1536]; Mp out: bf16 [b][88][1024].
__global__ __launch_bounds__(256) void k_gru_step(
    int t,
    const unsigned short* __restrict__ pre, const float* __restrict__ Wt,
    const float* __restrict__ bhh32,
    const float* __restrict__ h_prev, float* __restrict__ h_next,
    unsigned short* __restrict__ Mp)
{
    __shared__ float hs[16][513];
    const int tid = threadIdx.x;
    const int d  = blockIdx.z;
    const int b0 = blockIdx.y * 16;
    const int j0 = blockIdx.x * 32;
    #pragma unroll
    for (int u = 0; u < 32; ++u) {
        int e = u * 256 + tid;
        int bb = e >> 9, k = e & 511;
        hs[bb][k] = h_prev[(((long)d * 128 + b0 + bb) << 9) + k];
    }
    __syncthreads();
    const int jq = tid & 15, bg = tid >> 4;
    const int j = j0 + jq * 2;
    const int b = b0 + bg;
    const float* wr = Wt + (long)d * 786432 + j;
    const float* wz = wr + 262144;
    const float* wn = wz + 262144;
    float ar0=0.f, ar1=0.f, az0=0.f, az1=0.f, an0=0.f, an1=0.f;
    #pragma unroll 8
    for (int k = 0; k < 512; ++k) {
        float hv = hs[bg][k];
        float2 r2 = *(const float2*)(wr + (k << 9));
        float2 z2 = *(const float2*)(wz + (k << 9));
        float2 n2 = *(const float2*)(wn + (k << 9));
        ar0 += r2.x * hv; ar1 += r2.y * hv;
        az0 += z2.x * hv; az1 += z2.y * hv;
        an0 += n2.x * hv; an1 += n2.y * hv;
    }
    const int ti = d ? (T_SEQ - 1 - t) : t;
    const unsigned short* pb = pre + (long)d * 15728640 + ((long)b * T_SEQ + ti) * 1536 + j;
    const float* bh = bhh32 + d * 1536 + j;
    float* hn = h_next + (((long)d * 128 + b) << 9) + j;
    unsigned short* mp = Mp + (long)b * 90112 + (long)(4 + ti) * 1024 + d * 512 + j;
    #pragma unroll
    for (int u = 0; u < 2; ++u) {
        float gr = (u ? ar1 : ar0) + bh[u];
        float gz = (u ? az1 : az0) + bh[512 + u];
        float gn = (u ? an1 : an0) + bh[1024 + u];
        float r = 1.f / (1.f + expf(-(bf2f(pb[u]) + gr)));
        float z = 1.f / (1.f + expf(-(bf2f(pb[512 + u]) + gz)));
        float n = tanhf(bf2f(pb[1024 + u]) + r * gn);
        float hnew = (1.f - z) * n + z * hs[bg][j + u];
        hn[u] = hnew;
        mp[u] = f2bf(hnew);
    }
}

// Mask Mp in place (bf16 * {0,1} is lossless) and compute mean over valid steps.
__global__ __launch_bounds__(256) void k_mask_mean(
    unsigned short* __restrict__ Mp, const void* __restrict__ mask,
    const int* __restrict__ lengths, float* __restrict__ mean, const int* __restrict__ dtf)
{
    const int f32m = *dtf;
    const int b = blockIdx.y;
    const int c = blockIdx.x * 256 + threadIdx.x;
    float acc = 0.f;
    unsigned short* base = Mp + (long)b * 90112 + 4096 + c;
    for (int t = 0; t < T_SEQ; ++t) {
        float m = ldsc(mask, b * T_SEQ + t, f32m);
        float v = bf2f(base[t * 1024]) * m;
        base[t * 1024] = f2bf(v);
        acc += v;
    }
    mean[b * 1024 + c] = acc / (float)lengths[b];
}

// Conv epilogue over bf16 D: c[b,kf,t] = sum_i D[b, t-w+1+i, i*512+kf]; relu(bias+max_t).
__global__ __launch_bounds__(256) void k_conv_epi(
    const unsigned short* __restrict__ D, const void* __restrict__ cb,
    float* __restrict__ con, int w, int widx, const int* __restrict__ dtf)
{
    const int f32m = *dtf;
    const int b  = blockIdx.y;
    const int kf = blockIdx.x * 256 + threadIdx.x;
    const int N  = w * 512;
    const unsigned short* Db = D + (long)b * T_SEQ * N;
    float mx = -1e30f;
    for (int t = 0; t < T_SEQ + w - 1; ++t) {
        float s = 0.f;
        for (int i = 0; i < w; ++i) {
            int tau = t - w + 1 + i;
            if (tau >= 0 && tau < T_SEQ) s += bf2f(Db[(long)tau * N + i * 512 + kf]);
        }
        mx = fmaxf(mx, s);
    }
    con[b * 2048 + widx * 512 + kf] = fmaxf(0.f, mx + ldsc(cb, kf, f32m));
}

// Assemble map input: [mean_gru(1024) | con(2048) | videos_origin(2048)].
__global__ __launch_bounds__(256) void k_gather(
    const float* __restrict__ mean, const float* __restrict__ con,
    const void* __restrict__ vo, float* __restrict__ fin, const int* __restrict__ dtf)
{
    const int f32m = *dtf;
    int e = blockIdx.x * 256 + threadIdx.x;     // < 655360
    int b = e / 5120, k = e - b * 5120;
    float v;
    if (k < 1024)      v = mean[b * 1024 + k];
    else if (k < 3072) v = con[b * 2048 + (k - 1024)];
    else               v = ldsc(vo, b * 2048 + (k - 3072), f32m);
    fin[e] = v;
}

// BN (eval) + row L2-normalize; output dtype follows the probed flag.
__global__ __launch_bounds__(256) void k_bn_norm(
    const float* __restrict__ feat, const void* __restrict__ gamma,
    const void* __restrict__ beta, void* __restrict__ out, const int* __restrict__ dtf)
{
    const int f32m = *dtf;
    const int b = blockIdx.x, tid = threadIdx.x;
    const float inv_c = 1.f / sqrtf(1.f + 1e-5f);
    float y[8]; float ss = 0.f;
    #pragma unroll
    for (int u = 0; u < 8; ++u) {
        int o = u * 256 + tid;
        float v = feat[b * 2048 + o] * inv_c * ldsc(gamma, o, f32m) + ldsc(beta, o, f32m);
        y[u] = v; ss += v * v;
    }
    #pragma unroll
    for (int off = 32; off >= 1; off >>= 1) ss += __shfl_down(ss, off, 64);
    __shared__ float rs[4];
    if ((tid & 63) == 0) rs[tid >> 6] = ss;
    __syncthreads();
    float rn = 1.f / sqrtf(rs[0] + rs[1] + rs[2] + rs[3]);
    #pragma unroll
    for (int u = 0; u < 8; ++u) {
        int o = u * 256 + tid;
        float v = y[u] * rn;
        if (f32m) ((float*)out)[b * 2048 + o] = v;
        else      ((unsigned short*)out)[b * 2048 + o] = f2bf(v);
    }
}

extern "C" void kernel_launch(void* const* d_in, const int* in_sizes, int n_in,
                              void* d_out, int out_size, void* d_ws, size_t ws_size,
                              hipStream_t stream)
{
    const void* videos  = d_in[0];
    const void* vorigin = d_in[1];
    const int*  lengths = (const int*)d_in[2];
    const void* mask    = d_in[3];
    // d_in[4] gru_text_out: unused by the reference
    const void* Wih_f = d_in[5];
    const void* Whh_f = d_in[6];
    const void* bih_f = d_in[7];
    const void* bhh_f = d_in[8];
    const void* Wih_b = d_in[9];
    const void* Whh_b = d_in[10];
    const void* bih_b = d_in[11];
    const void* bhh_b = d_in[12];
    // d_in[13..16] attention: dead (softmax over size-1 axis == 1)
    const void* cw[4] = { d_in[17], d_in[19], d_in[21], d_in[23] };
    const void* cb[4] = { d_in[18], d_in[20], d_in[22], d_in[24] };
    const void* map_W = d_in[25];
    const void* map_b = d_in[26];
    const void* gamma = d_in[27];
    const void* beta  = d_in[28];

    // --- workspace layout (bytes), total 98,578,448 B ---
    unsigned char* W = (unsigned char*)d_ws;
    unsigned short* pre  = (unsigned short*)W;               // 2*10240*1536 bf16 = 62,914,560 B (conv D aliases: 10240*2560 bf16 = 52.4 MB)
    unsigned short* Mp   = (unsigned short*)(W + 62914560);  // 128*88*1024 bf16 = 23,068,672 B
    float* h0    = (float*)(W + 85983232);                   // 2*128*512 f32
    float* h1    = h0 + 131072;
    float* Wt    = (float*)(W + 87031808);                   // 2*3*512*512 f32
    float* bhh32 = (float*)(W + 93323264);                   // 3072 f32
    float* mean  = (float*)(W + 93335552);                   // 128*1024 f32
    float* con   = (float*)(W + 93859840);                   // 128*2048 f32
    float* fin   = (float*)(W + 94908416);                   // 128*5120 f32
    float* feat  = (float*)(W + 97529856);                   // 128*2048 f32
    int*   dtf   = (int*)(W + 98578432);                     // dtype flag

    k_probe<<<1, 64, 0, stream>>>((const unsigned short*)videos, dtf);

    hipMemsetAsync(Mp, 0, 23068672, stream);   // zero padding rows of Mp (bf16 zero == 0x0000)
    hipMemsetAsync(h0, 0, 1048576, stream);    // both h buffers

    k_prep<<<6144, 256, 0, stream>>>(Whh_f, Whh_b, bhh_f, bhh_b, Wt, bhh32, dtf);

    // GRU input projection: pre[d][b*80+t][1536] = videos @ Wih_d^T + bih_d  (bf16 out)
    gemm_nt<2, 1><<<dim3(24, 80), 256, 0, stream>>>(
        videos, 0l, 10240, 0l, 2048,
        Wih_f, Wih_b, 1536, 1536, 2048l, 0l,
        bih_f, bih_b, 1,
        pre, 15728640l, 1536l, 2048, dtf);

    for (int t = 0; t < T_SEQ; ++t) {
        float* hp = (t & 1) ? h1 : h0;
        float* hn = (t & 1) ? h0 : h1;
        k_gru_step<<<dim3(16, 8, 2), 256, 0, stream>>>(t, pre, Wt, bhh32, hp, hn, Mp);
    }

    k_mask_mean<<<dim3(4, 128), 256, 0, stream>>>(Mp, mask, lengths, mean, dtf);

    // Convs: D[(b,tau),(i*512+kf)] = sum_d Mp[b,tau,d]*cw[kf,i,d] (bf16 out into pre region)
    for (int wi = 0; wi < 4; ++wi) {
        int ww = wi + 2;
        int N  = ww * 512;
        gemm_nt<1, 1><<<dim3(N / 128, 80), 256, 0, stream>>>(
            Mp, 4096l, 80, 90112l, 1024,
            cw[wi], nullptr, 1 << 30, 512, (long)(ww * 1024), 1024l,
            nullptr, nullptr, 0,
            pre /*D*/, 0l, (long)N, 1024, dtf);
        k_conv_epi<<<dim3(2, 128), 256, 0, stream>>>(pre, cb[wi], con, ww, wi, dtf);
    }

    k_gather<<<2560, 256, 0, stream>>>(mean, con, vorigin, fin, dtf);

    // feat = fin @ map_W^T + map_b  (f32 out)
    gemm_nt<0, 0><<<dim3(16, 1), 256, 0, stream>>>(
        fin, 0l, 128, 0l, 5120,
        map_W, nullptr, 1 << 30, 2048, 5120l, 0l,
        map_b, nullptr, 1,
        feat, 0l, 2048l, 5120, dtf);

    k_bn_norm<<<128, 256, 0, stream>>>(feat, gamma, beta, d_out, dtf);
}